// Round 7
// baseline (618.926 us; speedup 1.0000x reference)
//
#include <hip/hip_runtime.h>
#include <hip/hip_bf16.h>
#include <math.h>

typedef __attribute__((ext_vector_type(8))) short bf16x8;
typedef __attribute__((ext_vector_type(4))) float f32x4;

// ---------------- helpers ----------------

__device__ __forceinline__ short f2bf(float f) {           // RNE fp32->bf16
    unsigned u = __float_as_uint(f);
    u += 0x7fff + ((u >> 16) & 1);
    return (short)(u >> 16);
}
__device__ __forceinline__ float bf2f(unsigned short s) {
    return __uint_as_float(((unsigned)s) << 16);
}

__device__ __forceinline__ int load_idx(const void* ei, long long pos, int is64) {
    if (is64) return (int)((const long long*)ei)[pos];
    return ((const int*)ei)[pos];
}

// 1-thread kernel: decide whether edge_index is int64 (all high 32-bit words 0)
__global__ void detect_dtype(const unsigned* __restrict__ ei, int* flag) {
    int ok = (ei[1] == 0u) & (ei[3] == 0u) & (ei[5] == 0u) &
             (ei[7] == 0u) & (ei[9] == 0u) & (ei[11] == 0u);
    *flag = ok;
}

// ---------------- CSR build (once; edge list is layer-invariant) ----------------

// ILP-4: 4 edges per thread, fire-and-forget atomics
__global__ void hist_dst(const void* __restrict__ ei, const int* __restrict__ flag,
                         int* __restrict__ deg, int E, int N) {
    int is64 = *flag;
    int total = E + N;
    int t0 = (int)((blockIdx.x * (size_t)blockDim.x + threadIdx.x) * 4);
    if (t0 >= total) return;
    int cnt = total - t0; if (cnt > 4) cnt = 4;
    int d[4];
#pragma unroll
    for (int j = 0; j < 4; j++) {
        int t = t0 + j;
        if (j < cnt) d[j] = (t < E) ? load_idx(ei, (long long)E + t, is64) : (t - E);
    }
#pragma unroll
    for (int j = 0; j < 4; j++) if (j < cnt) atomicAdd(deg + d[j], 1);
}

__global__ void scan_block(const int* __restrict__ deg, int* __restrict__ pos,
                           int* __restrict__ bsum, int N) {
    __shared__ int buf[1024];
    int tid = threadIdx.x;
    int gid = blockIdx.x * 1024 + tid;
    int v = (gid < N) ? deg[gid] : 0;
    buf[tid] = v;
    __syncthreads();
#pragma unroll
    for (int off = 1; off < 1024; off <<= 1) {
        int t = (tid >= off) ? buf[tid - off] : 0;
        __syncthreads();
        buf[tid] += t;
        __syncthreads();
    }
    if (gid < N) pos[gid] = buf[tid] - v;     // exclusive within block
    if (tid == 1023) bsum[blockIdx.x] = buf[tid];
}

__global__ void scan_bsums(const int* __restrict__ bsum, int* __restrict__ boff,
                           int nb, int* __restrict__ rowptrN) {
    __shared__ int buf[256];
    __shared__ int carry;
    int tid = threadIdx.x;
    if (tid == 0) carry = 0;
    __syncthreads();
    for (int base = 0; base < nb; base += 256) {
        int v = (base + tid < nb) ? bsum[base + tid] : 0;
        buf[tid] = v;
        __syncthreads();
#pragma unroll
        for (int off = 1; off < 256; off <<= 1) {
            int t = (tid >= off) ? buf[tid - off] : 0;
            __syncthreads();
            buf[tid] += t;
            __syncthreads();
        }
        if (base + tid < nb) boff[base + tid] = buf[tid] - v + carry;
        __syncthreads();
        if (tid == 255) carry += buf[255];
        __syncthreads();
    }
    if (tid == 0) *rowptrN = carry;
}

__global__ void add_offsets(const int* __restrict__ boff, int* __restrict__ rowptr,
                            int* __restrict__ pos, int N) {
    int t = (int)(blockIdx.x * (size_t)blockDim.x + threadIdx.x);
    if (t >= N) return;
    int r = pos[t] + boff[t >> 10];
    rowptr[t] = r;
    pos[t] = r;
}

// ILP-4 scatter: 4 independent atomic round-trips in flight per thread
__global__ void scatter_src(const void* __restrict__ ei, const int* __restrict__ flag,
                            int* __restrict__ pos, int* __restrict__ srcs, int E, int N) {
    int is64 = *flag;
    int total = E + N;
    int t0 = (int)((blockIdx.x * (size_t)blockDim.x + threadIdx.x) * 4);
    if (t0 >= total) return;
    int cnt = total - t0; if (cnt > 4) cnt = 4;
    int s[4], d[4], p[4];
#pragma unroll
    for (int j = 0; j < 4; j++) {
        int t = t0 + j;
        if (j < cnt) {
            if (t < E) { s[j] = load_idx(ei, t, is64); d[j] = load_idx(ei, (long long)E + t, is64); }
            else       { s[j] = d[j] = t - E; }
        }
    }
#pragma unroll
    for (int j = 0; j < 4; j++) if (j < cnt) p[j] = atomicAdd(pos + d[j], 1);
#pragma unroll
    for (int j = 0; j < 4; j++) if (j < cnt) srcs[p[j]] = s[j];
}

// ---------------- MFMA GEMM + attention scalars ----------------
// C[N x 64] = X[N x K] @ W[K x 64]; wave computes a 16x64 tile via 16x16x32 bf16 MFMA.
// XT = float (layer 0) or unsigned short/bf16 (layer 1). H stored bf16.
template <int K, typename XT>
__global__ __launch_bounds__(256) void gemm_mfma(
        const XT* __restrict__ X, const float* __restrict__ W,
        const float* __restrict__ a_s, const float* __restrict__ a_d,
        unsigned short* __restrict__ Hbf,
        float* __restrict__ Sv, float* __restrict__ Dv, int N) {
    constexpr int KS = K / 32;
    int wid = threadIdx.x >> 6;
    int lane = threadIdx.x & 63;
    int base = blockIdx.x * 64 + wid * 16;
    if (base >= N) return;
    int l15 = lane & 15, lhi = lane >> 4;

    // B fragments from W (K x 64 row-major), converted to bf16
    bf16x8 bfrag[KS][4];
#pragma unroll
    for (int ks = 0; ks < KS; ks++)
#pragma unroll
        for (int ct = 0; ct < 4; ct++) {
            int col = ct * 16 + l15;
#pragma unroll
            for (int i = 0; i < 8; i++) {
                int k = ks * 32 + lhi * 8 + i;
                bfrag[ks][ct][i] = f2bf(W[k * 64 + col]);
            }
        }

    // A fragments from X (row-major, stride K)
    int row = base + l15; if (row >= N) row = N - 1;   // clamp; writes masked
    const XT* xr = X + (size_t)row * K + lhi * 8;
    bf16x8 afrag[KS];
#pragma unroll
    for (int ks = 0; ks < KS; ks++) {
        if constexpr (sizeof(XT) == 4) {
            float4 u0 = *(const float4*)(xr + ks * 32);
            float4 u1 = *(const float4*)(xr + ks * 32 + 4);
            afrag[ks][0] = f2bf(u0.x); afrag[ks][1] = f2bf(u0.y);
            afrag[ks][2] = f2bf(u0.z); afrag[ks][3] = f2bf(u0.w);
            afrag[ks][4] = f2bf(u1.x); afrag[ks][5] = f2bf(u1.y);
            afrag[ks][6] = f2bf(u1.z); afrag[ks][7] = f2bf(u1.w);
        } else {
            afrag[ks] = *(const bf16x8*)(xr + ks * 32);
        }
    }

    f32x4 acc[4] = {{0.f,0.f,0.f,0.f},{0.f,0.f,0.f,0.f},{0.f,0.f,0.f,0.f},{0.f,0.f,0.f,0.f}};
#pragma unroll
    for (int ks = 0; ks < KS; ks++)
#pragma unroll
        for (int ct = 0; ct < 4; ct++)
            acc[ct] = __builtin_amdgcn_mfma_f32_16x16x32_bf16(afrag[ks], bfrag[ks][ct], acc[ct], 0, 0, 0);

    float asv[4], adv[4];
#pragma unroll
    for (int ct = 0; ct < 4; ct++) { asv[ct] = a_s[ct * 16 + l15]; adv[ct] = a_d[ct * 16 + l15]; }

#pragma unroll
    for (int r = 0; r < 4; r++) {
        int grow = base + lhi * 4 + r;
        bool ok = grow < N;
        float sv = 0.f, dv = 0.f;
#pragma unroll
        for (int ct = 0; ct < 4; ct++) {
            float v = acc[ct][r];
            if (ok) Hbf[(size_t)grow * 64 + ct * 16 + l15] = (unsigned short)f2bf(v);
            sv = fmaf(v, asv[ct], sv);
            dv = fmaf(v, adv[ct], dv);
        }
#pragma unroll
        for (int off = 1; off < 16; off <<= 1) {
            sv += __shfl_xor(sv, off);
            dv += __shfl_xor(dv, off);
        }
        if (ok && l15 == 0) { Sv[grow] = sv; Dv[grow] = dv; }
    }
}

// ---------------- fused per-dst softmax aggregation, NN nodes per wave ----------------
// lane = channel; H is bf16 (128B coalesced row gathers).
// NN independent latency chains per wave: prologue loads, shfl reductions and the
// zero-padded branch-free gather loop (NN x ILP-8 = 32 outstanding row loads).
// Slow path (any deg>64; ~never for this graph): per-node online-softmax chunks.
template <bool CLS, int NN>
__global__ __launch_bounds__(256) void gat_agg(
        const int* __restrict__ rowptr, const int* __restrict__ srcs,
        const unsigned short* __restrict__ H, const float* __restrict__ Sv,
        const float* __restrict__ Dv, const float* __restrict__ b,
        unsigned short* __restrict__ OutRow,
        const float* __restrict__ Wc, const float* __restrict__ bc,
        float* __restrict__ out, int N) {
    int wv = (int)((blockIdx.x * (size_t)blockDim.x + threadIdx.x) >> 6);
    int lane = threadIdx.x & 63;
    int n0 = wv * NN;
    if (n0 >= N) return;

    int st[NN], dg[NN];
    bool fast = true;
#pragma unroll
    for (int i = 0; i < NN; i++) {
        int n = n0 + i;
        if (n < N) { st[i] = rowptr[n]; dg[i] = rowptr[n + 1] - st[i]; }
        else       { st[i] = 0; dg[i] = 0; }
        fast &= (dg[i] <= 64);
    }
    float dvv[NN];
#pragma unroll
    for (int i = 0; i < NN; i++) dvv[i] = (n0 + i < N) ? Dv[n0 + i] : 0.f;

    float acc[NN], den[NN];

    if (fast) {
        int s[NN]; float e[NN];
#pragma unroll
        for (int i = 0; i < NN; i++) {
            s[i] = 0; e[i] = -INFINITY;
            if (lane < dg[i]) {
                s[i] = srcs[st[i] + lane];
                float ev = Sv[s[i]] + dvv[i];
                e[i] = (ev > 0.f) ? ev : 0.2f * ev;
            }
        }
        float m[NN], p[NN];
#pragma unroll
        for (int i = 0; i < NN; i++) m[i] = e[i];
#pragma unroll
        for (int off = 32; off; off >>= 1)
#pragma unroll
            for (int i = 0; i < NN; i++) m[i] = fmaxf(m[i], __shfl_xor(m[i], off));
#pragma unroll
        for (int i = 0; i < NN; i++) {
            p[i] = (lane < dg[i]) ? __expf(e[i] - m[i]) : 0.f;   // pad lanes: exactly 0
            den[i] = p[i];
            acc[i] = 0.f;
        }
#pragma unroll
        for (int off = 32; off; off >>= 1)
#pragma unroll
            for (int i = 0; i < NN; i++) den[i] += __shfl_xor(den[i], off);

        int c8 = 0;
#pragma unroll
        for (int i = 0; i < NN; i++) { int c = (dg[i] + 7) & ~7; c8 = c > c8 ? c : c8; }
        for (int j = 0; j < c8; j += 8) {
#pragma unroll
            for (int u = 0; u < 8; u++) {
#pragma unroll
                for (int i = 0; i < NN; i++) {
                    float pj = __shfl(p[i], j + u);
                    int   ss = __shfl(s[i], j + u);
                    acc[i] = fmaf(pj, bf2f(H[(size_t)ss * 64 + lane]), acc[i]);
                }
            }
        }
    } else {
#pragma unroll
        for (int i = 0; i < NN; i++) {
            float m = -INFINITY;
            acc[i] = 0.f; den[i] = 0.f;
            int start = st[i], end = st[i] + dg[i];
            for (int cs = start; cs < end; cs += 64) {
                int cnt = end - cs; if (cnt > 64) cnt = 64;
                int s = 0;
                float e = -INFINITY;
                if (lane < cnt) {
                    s = srcs[cs + lane];
                    float ev = Sv[s] + dvv[i];
                    e = (ev > 0.f) ? ev : 0.2f * ev;
                }
                float cm = e;
#pragma unroll
                for (int off = 32; off; off >>= 1) cm = fmaxf(cm, __shfl_xor(cm, off));
                float nm = fmaxf(m, cm);
                float scale = __expf(m - nm);
                float p = (lane < cnt) ? __expf(e - nm) : 0.f;
                float ps = p;
#pragma unroll
                for (int off = 32; off; off >>= 1) ps += __shfl_xor(ps, off);
                den[i] = den[i] * scale + ps;
                acc[i] *= scale;
                int cnt8 = (cnt + 7) & ~7;
                for (int j = 0; j < cnt8; j += 8) {
#pragma unroll
                    for (int u = 0; u < 8; u++) {
                        float pj = __shfl(p, j + u);
                        int   ss = __shfl(s, j + u);
                        acc[i] = fmaf(pj, bf2f(H[(size_t)ss * 64 + lane]), acc[i]);
                    }
                }
                m = nm;
            }
        }
    }

    float v[NN];
#pragma unroll
    for (int i = 0; i < NN; i++) {
        float t = acc[i] / (den[i] + 1e-16f) + b[lane];
        v[i] = t > 0.f ? t : 0.f;               // relu
    }

    if constexpr (!CLS) {
#pragma unroll
        for (int i = 0; i < NN; i++) {
            int n = n0 + i;
            if (n < N) OutRow[(size_t)n * 64 + lane] = (unsigned short)f2bf(v[i]);
        }
    } else {
        float a[NN];
#pragma unroll
        for (int i = 0; i < NN; i++) a[i] = 0.f;
#pragma unroll
        for (int k = 0; k < 64; k++) {
            float w = (lane < 40) ? Wc[k * 40 + lane] : 0.f;
#pragma unroll
            for (int i = 0; i < NN; i++) a[i] = fmaf(__shfl(v[i], k), w, a[i]);
        }
#pragma unroll
        for (int i = 0; i < NN; i++) {
            float logit = (lane < 40) ? a[i] + bc[lane] : -INFINITY;
            float mm = logit;
#pragma unroll
            for (int off = 32; off; off >>= 1) mm = fmaxf(mm, __shfl_xor(mm, off));
            float ex = (lane < 40) ? __expf(logit - mm) : 0.f;
            float ssum = ex;
#pragma unroll
            for (int off = 32; off; off >>= 1) ssum += __shfl_xor(ssum, off);
            int n = n0 + i;
            if (n < N && lane < 40) out[(size_t)n * 40 + lane] = logit - mm - __logf(ssum);
        }
    }
}

// ---------------- launch ----------------

extern "C" void kernel_launch(void* const* d_in, const int* in_sizes, int n_in,
                              void* d_out, int out_size, void* d_ws, size_t ws_size,
                              hipStream_t stream) {
    const float* x   = (const float*)d_in[0];
    const void*  ei  = d_in[1];
    const float* W0  = (const float*)d_in[2];
    const float* as0 = (const float*)d_in[3];
    const float* ad0 = (const float*)d_in[4];
    const float* b0  = (const float*)d_in[5];
    const float* W1  = (const float*)d_in[6];
    const float* as1 = (const float*)d_in[7];
    const float* ad1 = (const float*)d_in[8];
    const float* b1  = (const float*)d_in[9];
    const float* Wc  = (const float*)d_in[10];
    const float* bc  = (const float*)d_in[11];
    float* out = (float*)d_out;

    const int N = in_sizes[0] / 128;   // 100000
    const int E = in_sizes[1] / 2;     // 1600000
    const int TOT = E + N;             // with self loops
    const int NB = (N + 1023) / 1024;  // scan blocks

    char* w = (char*)d_ws;
    unsigned short* HAbf   = (unsigned short*)w; w += (size_t)N * 64 * 2;  // gemm output (bf16)
    unsigned short* HCbf   = (unsigned short*)w; w += (size_t)N * 64 * 2;  // agg0 output (bf16)
    float*          Sv     = (float*)w;          w += (size_t)N * 4;
    float*          Dv     = (float*)w;          w += (size_t)N * 4;
    int*            deg    = (int*)w;            w += (size_t)(N + 1) * 4;
    int*            rowptr = (int*)w;            w += (size_t)(N + 1) * 4;
    int*            pos    = (int*)w;            w += (size_t)N * 4;
    int*            srcs   = (int*)w;            w += (size_t)TOT * 4;
    int*            bsum   = (int*)w;            w += (size_t)NB * 4;
    int*            boff   = (int*)w;            w += (size_t)NB * 4;
    int*            flag   = (int*)w;            w += 256;

    const int B = 256;
    const int NN = 4;                            // nodes per wave in gat_agg
    const int wavesNeeded = (N + NN - 1) / NN;
    const int gAgg  = (wavesNeeded + 3) / 4;     // 4 waves per block
    const int gTile = (N + 63) / 64;             // 64 rows per block (4 waves x 16)
    const int gEdge4 = (TOT + 4 * B - 1) / (4 * B);  // 4 edges per thread

    // ---- CSR build (once; reused by both layers) ----
    detect_dtype<<<1, 1, 0, stream>>>((const unsigned*)ei, flag);
    hipMemsetAsync(deg, 0, (size_t)(N + 1) * 4, stream);
    hist_dst<<<gEdge4, B, 0, stream>>>(ei, flag, deg, E, N);
    scan_block<<<NB, 1024, 0, stream>>>(deg, pos, bsum, N);
    scan_bsums<<<1, 256, 0, stream>>>(bsum, boff, NB, rowptr + N);
    add_offsets<<<(N + B - 1) / B, B, 0, stream>>>(boff, rowptr, pos, N);
    scatter_src<<<gEdge4, B, 0, stream>>>(ei, flag, pos, srcs, E, N);

    // ---- layer 0 ----
    gemm_mfma<128, float><<<gTile, B, 0, stream>>>(x, W0, as0, ad0, HAbf, Sv, Dv, N);
    gat_agg<false, NN><<<gAgg, B, 0, stream>>>(rowptr, srcs, HAbf, Sv, Dv, b0,
                                               HCbf, nullptr, nullptr, nullptr, N);

    // ---- layer 1 (gemm reads bf16 rows) ----
    gemm_mfma<64, unsigned short><<<gTile, B, 0, stream>>>(HCbf, W1, as1, ad1, HAbf, Sv, Dv, N);
    gat_agg<true, NN><<<gAgg, B, 0, stream>>>(rowptr, srcs, HAbf, Sv, Dv, b1,
                                              nullptr, Wc, bc, out, N);
}

// Round 8
// 436.497 us; speedup vs baseline: 1.4179x; 1.4179x over previous
//
#include <hip/hip_runtime.h>
#include <hip/hip_bf16.h>
#include <math.h>

typedef __attribute__((ext_vector_type(8))) short bf16x8;
typedef __attribute__((ext_vector_type(4))) float f32x4;

// ---------------- helpers ----------------

__device__ __forceinline__ short f2bf(float f) {           // RNE fp32->bf16
    unsigned u = __float_as_uint(f);
    u += 0x7fff + ((u >> 16) & 1);
    return (short)(u >> 16);
}
__device__ __forceinline__ float bf2f(unsigned short s) {
    return __uint_as_float(((unsigned)s) << 16);
}

__device__ __forceinline__ int load_idx(const void* ei, long long pos, int is64) {
    if (is64) return (int)((const long long*)ei)[pos];
    return ((const int*)ei)[pos];
}

// 1-thread kernel: decide whether edge_index is int64 (all high 32-bit words 0)
__global__ void detect_dtype(const unsigned* __restrict__ ei, int* flag) {
    int ok = (ei[1] == 0u) & (ei[3] == 0u) & (ei[5] == 0u) &
             (ei[7] == 0u) & (ei[9] == 0u) & (ei[11] == 0u);
    *flag = ok;
}

// ---------------- CSR build (once; edge list is layer-invariant) ----------------

// ILP-4: 4 edges per thread, fire-and-forget atomics
__global__ void hist_dst(const void* __restrict__ ei, const int* __restrict__ flag,
                         int* __restrict__ deg, int E, int N) {
    int is64 = *flag;
    int total = E + N;
    int t0 = (int)((blockIdx.x * (size_t)blockDim.x + threadIdx.x) * 4);
    if (t0 >= total) return;
    int cnt = total - t0; if (cnt > 4) cnt = 4;
    int d[4];
#pragma unroll
    for (int j = 0; j < 4; j++) {
        int t = t0 + j;
        if (j < cnt) d[j] = (t < E) ? load_idx(ei, (long long)E + t, is64) : (t - E);
    }
#pragma unroll
    for (int j = 0; j < 4; j++) if (j < cnt) atomicAdd(deg + d[j], 1);
}

__global__ void scan_block(const int* __restrict__ deg, int* __restrict__ pos,
                           int* __restrict__ bsum, int N) {
    __shared__ int buf[1024];
    int tid = threadIdx.x;
    int gid = blockIdx.x * 1024 + tid;
    int v = (gid < N) ? deg[gid] : 0;
    buf[tid] = v;
    __syncthreads();
#pragma unroll
    for (int off = 1; off < 1024; off <<= 1) {
        int t = (tid >= off) ? buf[tid - off] : 0;
        __syncthreads();
        buf[tid] += t;
        __syncthreads();
    }
    if (gid < N) pos[gid] = buf[tid] - v;     // exclusive within block
    if (tid == 1023) bsum[blockIdx.x] = buf[tid];
}

__global__ void scan_bsums(const int* __restrict__ bsum, int* __restrict__ boff,
                           int nb, int* __restrict__ rowptrN) {
    __shared__ int buf[256];
    __shared__ int carry;
    int tid = threadIdx.x;
    if (tid == 0) carry = 0;
    __syncthreads();
    for (int base = 0; base < nb; base += 256) {
        int v = (base + tid < nb) ? bsum[base + tid] : 0;
        buf[tid] = v;
        __syncthreads();
#pragma unroll
        for (int off = 1; off < 256; off <<= 1) {
            int t = (tid >= off) ? buf[tid - off] : 0;
            __syncthreads();
            buf[tid] += t;
            __syncthreads();
        }
        if (base + tid < nb) boff[base + tid] = buf[tid] - v + carry;
        __syncthreads();
        if (tid == 255) carry += buf[255];
        __syncthreads();
    }
    if (tid == 0) *rowptrN = carry;
}

__global__ void add_offsets(const int* __restrict__ boff, int* __restrict__ rowptr,
                            int* __restrict__ pos, int N) {
    int t = (int)(blockIdx.x * (size_t)blockDim.x + threadIdx.x);
    if (t >= N) return;
    int r = pos[t] + boff[t >> 10];
    rowptr[t] = r;
    pos[t] = r;
}

// ILP-4 scatter: 4 independent atomic round-trips in flight per thread
__global__ void scatter_src(const void* __restrict__ ei, const int* __restrict__ flag,
                            int* __restrict__ pos, int* __restrict__ srcs, int E, int N) {
    int is64 = *flag;
    int total = E + N;
    int t0 = (int)((blockIdx.x * (size_t)blockDim.x + threadIdx.x) * 4);
    if (t0 >= total) return;
    int cnt = total - t0; if (cnt > 4) cnt = 4;
    int s[4], d[4], p[4];
#pragma unroll
    for (int j = 0; j < 4; j++) {
        int t = t0 + j;
        if (j < cnt) {
            if (t < E) { s[j] = load_idx(ei, t, is64); d[j] = load_idx(ei, (long long)E + t, is64); }
            else       { s[j] = d[j] = t - E; }
        }
    }
#pragma unroll
    for (int j = 0; j < 4; j++) if (j < cnt) p[j] = atomicAdd(pos + d[j], 1);
#pragma unroll
    for (int j = 0; j < 4; j++) if (j < cnt) srcs[p[j]] = s[j];
}

// ---------------- MFMA GEMM + attention scalars ----------------
// C[N x 64] = X[N x K] @ W[K x 64]; wave computes a 16x64 tile via 16x16x32 bf16 MFMA.
// XT = float (layer 0) or unsigned short/bf16 (layer 1). H stored bf16.
template <int K, typename XT>
__global__ __launch_bounds__(256) void gemm_mfma(
        const XT* __restrict__ X, const float* __restrict__ W,
        const float* __restrict__ a_s, const float* __restrict__ a_d,
        unsigned short* __restrict__ Hbf,
        float* __restrict__ Sv, float* __restrict__ Dv, int N) {
    constexpr int KS = K / 32;
    int wid = threadIdx.x >> 6;
    int lane = threadIdx.x & 63;
    int base = blockIdx.x * 64 + wid * 16;
    if (base >= N) return;
    int l15 = lane & 15, lhi = lane >> 4;

    // B fragments from W (K x 64 row-major), converted to bf16
    bf16x8 bfrag[KS][4];
#pragma unroll
    for (int ks = 0; ks < KS; ks++)
#pragma unroll
        for (int ct = 0; ct < 4; ct++) {
            int col = ct * 16 + l15;
#pragma unroll
            for (int i = 0; i < 8; i++) {
                int k = ks * 32 + lhi * 8 + i;
                bfrag[ks][ct][i] = f2bf(W[k * 64 + col]);
            }
        }

    // A fragments from X (row-major, stride K)
    int row = base + l15; if (row >= N) row = N - 1;   // clamp; writes masked
    const XT* xr = X + (size_t)row * K + lhi * 8;
    bf16x8 afrag[KS];
#pragma unroll
    for (int ks = 0; ks < KS; ks++) {
        if constexpr (sizeof(XT) == 4) {
            float4 u0 = *(const float4*)(xr + ks * 32);
            float4 u1 = *(const float4*)(xr + ks * 32 + 4);
            afrag[ks][0] = f2bf(u0.x); afrag[ks][1] = f2bf(u0.y);
            afrag[ks][2] = f2bf(u0.z); afrag[ks][3] = f2bf(u0.w);
            afrag[ks][4] = f2bf(u1.x); afrag[ks][5] = f2bf(u1.y);
            afrag[ks][6] = f2bf(u1.z); afrag[ks][7] = f2bf(u1.w);
        } else {
            afrag[ks] = *(const bf16x8*)(xr + ks * 32);
        }
    }

    f32x4 acc[4] = {{0.f,0.f,0.f,0.f},{0.f,0.f,0.f,0.f},{0.f,0.f,0.f,0.f},{0.f,0.f,0.f,0.f}};
#pragma unroll
    for (int ks = 0; ks < KS; ks++)
#pragma unroll
        for (int ct = 0; ct < 4; ct++)
            acc[ct] = __builtin_amdgcn_mfma_f32_16x16x32_bf16(afrag[ks], bfrag[ks][ct], acc[ct], 0, 0, 0);

    float asv[4], adv[4];
#pragma unroll
    for (int ct = 0; ct < 4; ct++) { asv[ct] = a_s[ct * 16 + l15]; adv[ct] = a_d[ct * 16 + l15]; }

#pragma unroll
    for (int r = 0; r < 4; r++) {
        int grow = base + lhi * 4 + r;
        bool ok = grow < N;
        float sv = 0.f, dv = 0.f;
#pragma unroll
        for (int ct = 0; ct < 4; ct++) {
            float v = acc[ct][r];
            if (ok) Hbf[(size_t)grow * 64 + ct * 16 + l15] = (unsigned short)f2bf(v);
            sv = fmaf(v, asv[ct], sv);
            dv = fmaf(v, adv[ct], dv);
        }
#pragma unroll
        for (int off = 1; off < 16; off <<= 1) {
            sv += __shfl_xor(sv, off);
            dv += __shfl_xor(dv, off);
        }
        if (ok && l15 == 0) { Sv[grow] = sv; Dv[grow] = dv; }
    }
}

// ---------------- fused per-dst softmax aggregation, paired-edge dword gather ----------------
// One wave per dst node. Prologue: lane = edge slot (p, src). Gather: lane = (half, cp):
// cp = lane&31 indexes a CHANNEL PAIR (dword of 2 bf16), half = lane>>5 selects
// even/odd edge of each pair-step -> one dword load advances 2 edges. Final
// shfl_xor(32) merges the two halves. Pad lanes carry p=0,s=0 (exact no-op).
template <bool CLS>
__global__ __launch_bounds__(256) void gat_agg(
        const int* __restrict__ rowptr, const int* __restrict__ srcs,
        const unsigned short* __restrict__ H, const float* __restrict__ Sv,
        const float* __restrict__ Dv, const float* __restrict__ b,
        unsigned short* __restrict__ OutRow,
        const float* __restrict__ Wc, const float* __restrict__ bc,
        float* __restrict__ out, int N) {
    int node = (int)((blockIdx.x * (size_t)blockDim.x + threadIdx.x) >> 6);
    int lane = threadIdx.x & 63;
    if (node >= N) return;
    int start = rowptr[node], end = rowptr[node + 1];
    int deg = end - start;
    float dvv = Dv[node];
    int cp = lane & 31, half = lane >> 5;

    float aLo = 0.f, aHi = 0.f, den = 0.f;

    if (deg <= 64) {
        // ---- prologue: lane = edge slot ----
        int sj = 0;
        float e = -INFINITY;
        if (lane < deg) {
            sj = srcs[start + lane];
            float ev = Sv[sj] + dvv;
            e = (ev > 0.f) ? ev : 0.2f * ev;
        }
        float m = e;
#pragma unroll
        for (int off = 32; off; off >>= 1) m = fmaxf(m, __shfl_xor(m, off));
        float p = (lane < deg) ? __expf(e - m) : 0.f;   // pad lanes: exactly 0
        den = p;
#pragma unroll
        for (int off = 32; off; off >>= 1) den += __shfl_xor(den, off);

        // ---- paired-edge dword gather ----
        const unsigned* Hrow = (const unsigned*)H;       // dword view: node*32 + cp
        int P8 = (((deg + 1) >> 1) + 7) & ~7;            // edge pairs, rounded to 8
        for (int pi = 0; pi < P8; pi += 8) {
#pragma unroll
            for (int u = 0; u < 8; u++) {
                int idx = ((pi + u) << 1) + half;        // this half's edge
                float pj = __shfl(p, idx);
                int   ss = __shfl(sj, idx);
                unsigned uu = Hrow[(size_t)ss * 32 + cp];
                aLo = fmaf(pj, __uint_as_float(uu << 16), aLo);
                aHi = fmaf(pj, __uint_as_float(uu & 0xffff0000u), aHi);
            }
        }
        aLo += __shfl_xor(aLo, 32);
        aHi += __shfl_xor(aHi, 32);
    } else {
        // ---- slow path (deg>64): online-softmax chunks, per-channel layout ----
        float m = -INFINITY, acc = 0.f;
        for (int cs = start; cs < end; cs += 64) {
            int cnt = end - cs; if (cnt > 64) cnt = 64;
            int s = 0;
            float e = -INFINITY;
            if (lane < cnt) {
                s = srcs[cs + lane];
                float ev = Sv[s] + dvv;
                e = (ev > 0.f) ? ev : 0.2f * ev;
            }
            float cm = e;
#pragma unroll
            for (int off = 32; off; off >>= 1) cm = fmaxf(cm, __shfl_xor(cm, off));
            float nm = fmaxf(m, cm);
            float scale = __expf(m - nm);
            float p = (lane < cnt) ? __expf(e - nm) : 0.f;
            float ps = p;
#pragma unroll
            for (int off = 32; off; off >>= 1) ps += __shfl_xor(ps, off);
            den = den * scale + ps;
            acc *= scale;
            int cnt8 = (cnt + 7) & ~7;
            for (int j = 0; j < cnt8; j += 8) {
#pragma unroll
                for (int u = 0; u < 8; u++) {
                    float pj = __shfl(p, j + u);
                    int   ss = __shfl(s, j + u);
                    acc = fmaf(pj, bf2f(H[(size_t)ss * 64 + lane]), acc);
                }
            }
            m = nm;
        }
        // convert per-channel layout -> pair layout
        aLo = __shfl(acc, cp * 2);
        aHi = __shfl(acc, cp * 2 + 1);
    }

    // ---- epilogue in pair layout: lane cp holds channels 2cp, 2cp+1 ----
    float rden = 1.0f / (den + 1e-16f);
    float2 bb = *(const float2*)(b + cp * 2);
    float vLo = fmaf(aLo, rden, bb.x); vLo = vLo > 0.f ? vLo : 0.f;
    float vHi = fmaf(aHi, rden, bb.y); vHi = vHi > 0.f ? vHi : 0.f;

    if constexpr (!CLS) {
        if (half == 0) {
            unsigned pack = ((unsigned)(unsigned short)f2bf(vHi) << 16) |
                            (unsigned short)f2bf(vLo);
            *(unsigned*)(OutRow + (size_t)node * 64 + cp * 2) = pack;
        }
    } else {
        float a = 0.f;
#pragma unroll
        for (int k = 0; k < 32; k++) {
            float h0 = __shfl(vLo, k);                   // channel 2k
            float h1 = __shfl(vHi, k);                   // channel 2k+1
            float w0 = (lane < 40) ? Wc[(2 * k) * 40 + lane] : 0.f;
            float w1 = (lane < 40) ? Wc[(2 * k + 1) * 40 + lane] : 0.f;
            a = fmaf(h0, w0, a);
            a = fmaf(h1, w1, a);
        }
        float logit = (lane < 40) ? a + bc[lane] : -INFINITY;
        float mm = logit;
#pragma unroll
        for (int off = 32; off; off >>= 1) mm = fmaxf(mm, __shfl_xor(mm, off));
        float ex = (lane < 40) ? __expf(logit - mm) : 0.f;
        float ssum = ex;
#pragma unroll
        for (int off = 32; off; off >>= 1) ssum += __shfl_xor(ssum, off);
        if (lane < 40) out[(size_t)node * 40 + lane] = logit - mm - __logf(ssum);
    }
}

// ---------------- launch ----------------

extern "C" void kernel_launch(void* const* d_in, const int* in_sizes, int n_in,
                              void* d_out, int out_size, void* d_ws, size_t ws_size,
                              hipStream_t stream) {
    const float* x   = (const float*)d_in[0];
    const void*  ei  = d_in[1];
    const float* W0  = (const float*)d_in[2];
    const float* as0 = (const float*)d_in[3];
    const float* ad0 = (const float*)d_in[4];
    const float* b0  = (const float*)d_in[5];
    const float* W1  = (const float*)d_in[6];
    const float* as1 = (const float*)d_in[7];
    const float* ad1 = (const float*)d_in[8];
    const float* b1  = (const float*)d_in[9];
    const float* Wc  = (const float*)d_in[10];
    const float* bc  = (const float*)d_in[11];
    float* out = (float*)d_out;

    const int N = in_sizes[0] / 128;   // 100000
    const int E = in_sizes[1] / 2;     // 1600000
    const int TOT = E + N;             // with self loops
    const int NB = (N + 1023) / 1024;  // scan blocks

    char* w = (char*)d_ws;
    unsigned short* HAbf   = (unsigned short*)w; w += (size_t)N * 64 * 2;  // gemm output (bf16)
    unsigned short* HCbf   = (unsigned short*)w; w += (size_t)N * 64 * 2;  // agg0 output (bf16)
    float*          Sv     = (float*)w;          w += (size_t)N * 4;
    float*          Dv     = (float*)w;          w += (size_t)N * 4;
    int*            deg    = (int*)w;            w += (size_t)(N + 1) * 4;
    int*            rowptr = (int*)w;            w += (size_t)(N + 1) * 4;
    int*            pos    = (int*)w;            w += (size_t)N * 4;
    int*            srcs   = (int*)w;            w += (size_t)TOT * 4;
    int*            bsum   = (int*)w;            w += (size_t)NB * 4;
    int*            boff   = (int*)w;            w += (size_t)NB * 4;
    int*            flag   = (int*)w;            w += 256;

    const int B = 256;
    const int gRow   = (N + 3) / 4;              // wave per node
    const int gTile  = (N + 63) / 64;            // 64 rows per block (4 waves x 16)
    const int gEdge4 = (TOT + 4 * B - 1) / (4 * B);  // 4 edges per thread

    // ---- CSR build (once; reused by both layers) ----
    detect_dtype<<<1, 1, 0, stream>>>((const unsigned*)ei, flag);
    hipMemsetAsync(deg, 0, (size_t)(N + 1) * 4, stream);
    hist_dst<<<gEdge4, B, 0, stream>>>(ei, flag, deg, E, N);
    scan_block<<<NB, 1024, 0, stream>>>(deg, pos, bsum, N);
    scan_bsums<<<1, 256, 0, stream>>>(bsum, boff, NB, rowptr + N);
    add_offsets<<<(N + B - 1) / B, B, 0, stream>>>(boff, rowptr, pos, N);
    scatter_src<<<gEdge4, B, 0, stream>>>(ei, flag, pos, srcs, E, N);

    // ---- layer 0 ----
    gemm_mfma<128, float><<<gTile, B, 0, stream>>>(x, W0, as0, ad0, HAbf, Sv, Dv, N);
    gat_agg<false><<<gRow, B, 0, stream>>>(rowptr, srcs, HAbf, Sv, Dv, b0,
                                           HCbf, nullptr, nullptr, nullptr, N);

    // ---- layer 1 (gemm reads bf16 rows) ----
    gemm_mfma<64, unsigned short><<<gTile, B, 0, stream>>>(HCbf, W1, as1, ad1, HAbf, Sv, Dv, N);
    gat_agg<true><<<gRow, B, 0, stream>>>(rowptr, srcs, HAbf, Sv, Dv, b1,
                                          nullptr, Wc, bc, out, N);
}